// Round 3
// baseline (543.987 us; speedup 1.0000x reference)
//
#include <hip/hip_runtime.h>
#include <stdint.h>

// DecoderLayer: B=2, S=2048, DIM=1024, H=16, DH=64, DFF=2048
//  h1 = MHA(de_x, de_x, de_x, causal)   (shared weights Wq,Wk,Wv)
//  h2 = MHA(en_x, en_x, h1, none)
//  y  = relu(h2@W1+b1)@W2 + b2
// Round 3: (a) battle-tested MFMA builtin mfma_f32_16x16x16bf16_1k (short4),
// (b) runtime dtype probe (f32 vs bf16 device buffers) with ingest-convert to
// canonical bf16 workspace and dtype-matched output store.

#define DEV static __device__ __forceinline__

typedef __attribute__((ext_vector_type(4))) short bf16x4;            // MFMA operand
typedef __attribute__((ext_vector_type(8))) unsigned short u16x8;    // staging vec
typedef __attribute__((ext_vector_type(4))) float f32x4;

DEV float bf2f(uint16_t u) { union { uint32_t u; float f; } v; v.u = ((uint32_t)u) << 16; return v.f; }
DEV uint16_t f2bf(float f) {
  union { float f; uint32_t u; } v; v.f = f;
  uint32_t r = v.u + 0x7fffu + ((v.u >> 16) & 1u);
  return (uint16_t)(r >> 16);
}

DEV f32x4 mfma16(bf16x4 a, bf16x4 b, f32x4 c) {
  return __builtin_amdgcn_mfma_f32_16x16x16bf16_1k(a, b, c, 0, 0, 0);
}

// XOR swizzle: 16B slot s of row r lives at slot (s ^ (r&7)).
DEV int swz(int row, int slot) { return slot ^ (row & 7); }

// stage one 16B chunk: global (row-major) -> LDS (swizzled). rows are 64 bf16 = 128B.
DEV void stage16(const uint16_t* __restrict__ g, uint16_t* l, int row, int slot) {
  u16x8 v = *(const u16x8*)g;
  *(u16x8*)&l[(row * 8 + swz(row, slot)) * 8] = v;
}

// read a 4-element k-fragment (8B) from a swizzled 64-col tile row.
// k0 = element offset in row (multiple of 4).
DEV bf16x4 frag4(const uint16_t* l, int row, int k0) {
  int byte = k0 * 2;
  int slot = byte >> 4, sub = byte & 15;
  return *(const bf16x4*)((const char*)l + row * 128 + (swz(row, slot) << 4) + sub);
}

// ---------------- dtype probe ----------------
// f32 buffers: word1 of mask = bits(1.0f) = 0x3F800000 (low16 == 0)
// bf16 buffers: word1 = (mask[2]=1, mask[3]=1) = 0x3F803F80 (low16 != 0)
__global__ void probe_k(const uint32_t* __restrict__ mask, uint32_t* __restrict__ flag) {
  flag[0] = (mask[1] & 0xFFFFu) ? 1u : 0u;   // 1 = bf16, 0 = f32
}

// ---------------- ingest convert: (f32|bf16) -> bf16 ----------------
__global__ __launch_bounds__(256) void cvt_k(const void* __restrict__ src,
                                             uint16_t* __restrict__ dst, int n,
                                             const uint32_t* __restrict__ flag) {
  const int isbf = (int)flag[0];
  const float* sf = (const float*)src;
  const uint16_t* su = (const uint16_t*)src;
  for (int i = blockIdx.x * 256 + threadIdx.x; i < n; i += gridDim.x * 256)
    dst[i] = isbf ? su[i] : f2bf(sf[i]);
}

// ---------------- transpose: in[b][R][C] -> out[b][C][R], out bf16 ----------------
__global__ __launch_bounds__(256) void transpose_k(const void* __restrict__ in_,
                                                   uint16_t* __restrict__ out, int R, int C,
                                                   const uint32_t* __restrict__ flag) {
  __shared__ uint16_t t[32][33];
  const int isbf = (int)flag[0];
  const int b = blockIdx.z;
  const float* in_f = (const float*)in_ + (size_t)b * R * C;
  const uint16_t* in_u = (const uint16_t*)in_ + (size_t)b * R * C;
  out += (size_t)b * R * C;
  const int c0 = blockIdx.x * 32, r0 = blockIdx.y * 32;
  const int tx = threadIdx.x & 31, ty = threadIdx.x >> 5;
  for (int i = 0; i < 4; i++) {
    int r = ty + i * 8;
    size_t idx = (size_t)(r0 + r) * C + c0 + tx;
    t[r][tx] = isbf ? in_u[idx] : f2bf(in_f[idx]);
  }
  __syncthreads();
  for (int i = 0; i < 4; i++) {
    int r = ty + i * 8;
    out[(size_t)(c0 + r) * R + r0 + tx] = t[tx][r];
  }
}

// ---------------- fused QKV projection ----------------
// grid: (S/128, 3*16, B). proj = blockIdx.y>>4 (0=Q,1=K,2=V), h = blockIdx.y&15.
// A sources (bf16 canonical): [B*S,1024]. Wt*: [16][64][1024].
// Q,K out: [B,H,S,64]; V out transposed: [B,H,64,S]
__global__ __launch_bounds__(256) void proj_k(
    const uint16_t* __restrict__ A_qk, const uint16_t* __restrict__ A_v,
    const uint16_t* __restrict__ Wtq, const uint16_t* __restrict__ Wtk,
    const uint16_t* __restrict__ Wtv,
    uint16_t* __restrict__ Q, uint16_t* __restrict__ K, uint16_t* __restrict__ Vt) {
  __shared__ __attribute__((aligned(16))) uint16_t lA[128 * 64];
  __shared__ __attribute__((aligned(16))) uint16_t lB[64 * 64];
  const int tid = threadIdx.x, lane = tid & 63, wave = tid >> 6;
  const int g = lane >> 4;
  const int m0 = blockIdx.x * 128;
  const int h = blockIdx.y & 15, proj = blockIdx.y >> 4;
  const int b = blockIdx.z;
  const uint16_t* A = (proj == 2 ? A_v : A_qk) + (size_t)b * 2048 * 1024;
  const uint16_t* Bt = (proj == 0 ? Wtq : proj == 1 ? Wtk : Wtv) + (size_t)h * 64 * 1024;
  const int wm = wave >> 1, wn = wave & 1;
  f32x4 acc[4][2] = {};
  for (int kt = 0; kt < 1024; kt += 64) {
    __syncthreads();
    for (int i = 0; i < 4; i++) {   // A tile: 128 rows x 8 slots
      int c = i * 256 + tid, row = c >> 3, slot = c & 7;
      stage16(A + (size_t)(m0 + row) * 1024 + kt + slot * 8, lA, row, slot);
    }
    for (int i = 0; i < 2; i++) {   // B tile: 64 rows x 8 slots
      int c = i * 256 + tid, row = c >> 3, slot = c & 7;
      stage16(Bt + (size_t)row * 1024 + kt + slot * 8, lB, row, slot);
    }
    __syncthreads();
    for (int ks = 0; ks < 4; ks++) {
      int k0 = ks * 16 + g * 4;
      bf16x4 af[4], bfr[2];
      for (int fm = 0; fm < 4; fm++) af[fm] = frag4(lA, wm * 64 + fm * 16 + (lane & 15), k0);
      for (int fn = 0; fn < 2; fn++) bfr[fn] = frag4(lB, wn * 32 + fn * 16 + (lane & 15), k0);
      for (int fm = 0; fm < 4; fm++)
        for (int fn = 0; fn < 2; fn++)
          acc[fm][fn] = mfma16(af[fm], bfr[fn], acc[fm][fn]);
    }
  }
  uint16_t* outp = (proj == 0 ? Q : proj == 1 ? K : Vt);
  const size_t bh = (size_t)(b * 16 + h);
  for (int fm = 0; fm < 4; fm++)
    for (int fn = 0; fn < 2; fn++)
      for (int r = 0; r < 4; r++) {
        int s = m0 + wm * 64 + fm * 16 + g * 4 + r;
        int e = wn * 32 + fn * 16 + (lane & 15);
        uint16_t val = f2bf(acc[fm][fn][r]);
        if (proj == 2) outp[(bh * 64 + e) * 2048 + s] = val;   // V transposed
        else           outp[(bh * 2048 + s) * 64 + e] = val;
      }
}

// ---------------- flash attention ----------------
// grid: (S/64, H, B). 4 waves, each owns 16 q-rows. 64-key tiles.
template <int CAUSAL>
__global__ __launch_bounds__(256) void attn_k(const uint16_t* __restrict__ Q,
                                              const uint16_t* __restrict__ K,
                                              const uint16_t* __restrict__ Vt,
                                              uint16_t* __restrict__ O) {
  __shared__ __attribute__((aligned(16))) uint16_t lK[64 * 64];
  __shared__ __attribute__((aligned(16))) uint16_t lV[64 * 64];
  __shared__ __attribute__((aligned(16))) uint16_t lP[4][16 * 64];
  const int tid = threadIdx.x, lane = tid & 63, wave = tid >> 6;
  const int g = lane >> 4;
  const int qt = blockIdx.x, h = blockIdx.y, b = blockIdx.z;
  const size_t bh = (size_t)(b * 16 + h);
  const uint16_t* Qg = Q + bh * 2048 * 64;
  const uint16_t* Kg = K + bh * 2048 * 64;
  const uint16_t* Vg = Vt + bh * 64 * 2048;
  const int q0 = qt * 64;
  bf16x4 qfr[4];
  {
    int row = q0 + wave * 16 + (lane & 15);
    for (int ks = 0; ks < 4; ks++)
      qfr[ks] = *(const bf16x4*)(Qg + (size_t)row * 64 + ks * 16 + g * 4);
  }
  f32x4 oacc[4] = {};
  float m_run[4], l_run[4];
  for (int r = 0; r < 4; r++) { m_run[r] = -INFINITY; l_run[r] = 0.f; }
  const int ktmax = CAUSAL ? qt : 31;
  for (int kt = 0; kt <= ktmax; kt++) {
    __syncthreads();
    for (int i = 0; i < 2; i++) {   // K tile [64 keys][64 f]
      int c = i * 256 + tid, row = c >> 3, slot = c & 7;
      stage16(Kg + (size_t)(kt * 64 + row) * 64 + slot * 8, lK, row, slot);
    }
    for (int i = 0; i < 2; i++) {   // V tile [64 dh][64 keys], global row stride 2048
      int c = i * 256 + tid, row = c >> 3, slot = c & 7;
      stage16(Vg + (size_t)row * 2048 + kt * 64 + slot * 8, lV, row, slot);
    }
    __syncthreads();
    f32x4 s[4] = {};
    for (int ks = 0; ks < 4; ks++) {
      int k0 = ks * 16 + g * 4;
      for (int nf = 0; nf < 4; nf++)
        s[nf] = mfma16(qfr[ks], frag4(lK, nf * 16 + (lane & 15), k0), s[nf]);
    }
    float pm[4][4], rmax[4];
    for (int r = 0; r < 4; r++) rmax[r] = -INFINITY;
    for (int nf = 0; nf < 4; nf++)
      for (int r = 0; r < 4; r++) {
        float v = s[nf][r] * 0.125f;   // 1/sqrt(64)
        if (CAUSAL && kt == qt) {
          int qloc = wave * 16 + g * 4 + r;
          int kloc = nf * 16 + (lane & 15);
          if (kloc > qloc) v = -1e9f;
        }
        pm[nf][r] = v;
        rmax[r] = fmaxf(rmax[r], v);
      }
    for (int m = 1; m < 16; m <<= 1)
      for (int r = 0; r < 4; r++) rmax[r] = fmaxf(rmax[r], __shfl_xor(rmax[r], m));
    float alpha[4], rsum[4];
    for (int r = 0; r < 4; r++) {
      float mn = fmaxf(m_run[r], rmax[r]);
      alpha[r] = __expf(m_run[r] - mn);
      m_run[r] = mn;
      rsum[r] = 0.f;
    }
    for (int nf = 0; nf < 4; nf++)
      for (int r = 0; r < 4; r++) {
        float p = __expf(pm[nf][r] - m_run[r]);
        rsum[r] += p;
        int row = g * 4 + r;             // q-row 0..15
        int col = nf * 16 + (lane & 15); // key 0..63
        *(uint16_t*)((char*)lP[wave] + row * 128 + (swz(row, col >> 3) << 4) + ((col & 7) << 1)) = f2bf(p);
      }
    for (int m = 1; m < 16; m <<= 1)
      for (int r = 0; r < 4; r++) rsum[r] += __shfl_xor(rsum[r], m);
    for (int r = 0; r < 4; r++) l_run[r] = l_run[r] * alpha[r] + rsum[r];
    for (int df = 0; df < 4; df++) {
      f32x4 t = oacc[df];
      for (int r = 0; r < 4; r++) t[r] *= alpha[r];
      oacc[df] = t;
    }
    for (int ks = 0; ks < 4; ks++) {
      int k0 = ks * 16 + g * 4;
      bf16x4 pa = frag4(lP[wave], lane & 15, k0);
      for (int df = 0; df < 4; df++)
        oacc[df] = mfma16(pa, frag4(lV, df * 16 + (lane & 15), k0), oacc[df]);
    }
  }
  for (int df = 0; df < 4; df++)
    for (int r = 0; r < 4; r++) {
      int srow = q0 + wave * 16 + g * 4 + r;
      int e = df * 16 + (lane & 15);
      O[((size_t)b * 2048 + srow) * 1024 + h * 64 + e] = f2bf(oacc[df][r] / l_run[r]);
    }
}

// ---------------- FFN GEMM: C[M,N] = A[M,K] @ Bt[N,K]^T (+bias bf16, relu) ----------------
template <int RELU>
__global__ __launch_bounds__(256) void ff_k(const uint16_t* __restrict__ A,
                                            const uint16_t* __restrict__ Bt,
                                            const uint16_t* __restrict__ bias,
                                            uint16_t* __restrict__ C, int Kdim, int N) {
  __shared__ __attribute__((aligned(16))) uint16_t lA[128 * 64];
  __shared__ __attribute__((aligned(16))) uint16_t lB[128 * 64];
  const int tid = threadIdx.x, lane = tid & 63, wave = tid >> 6;
  const int g = lane >> 4;
  const int m0 = blockIdx.x * 128, n0 = blockIdx.y * 128;
  const int wm = wave >> 1, wn = wave & 1;
  f32x4 acc[4][4] = {};
  for (int kt = 0; kt < Kdim; kt += 64) {
    __syncthreads();
    for (int i = 0; i < 4; i++) {
      int c = i * 256 + tid, row = c >> 3, slot = c & 7;
      stage16(A + (size_t)(m0 + row) * Kdim + kt + slot * 8, lA, row, slot);
    }
    for (int i = 0; i < 4; i++) {
      int c = i * 256 + tid, row = c >> 3, slot = c & 7;
      stage16(Bt + (size_t)(n0 + row) * Kdim + kt + slot * 8, lB, row, slot);
    }
    __syncthreads();
    for (int ks = 0; ks < 4; ks++) {
      int k0 = ks * 16 + g * 4;
      bf16x4 af[4], bfr[4];
      for (int fm = 0; fm < 4; fm++) af[fm] = frag4(lA, wm * 64 + fm * 16 + (lane & 15), k0);
      for (int fn = 0; fn < 4; fn++) bfr[fn] = frag4(lB, wn * 64 + fn * 16 + (lane & 15), k0);
      for (int fm = 0; fm < 4; fm++)
        for (int fn = 0; fn < 4; fn++)
          acc[fm][fn] = mfma16(af[fm], bfr[fn], acc[fm][fn]);
    }
  }
  for (int fm = 0; fm < 4; fm++)
    for (int fn = 0; fn < 4; fn++) {
      int col = n0 + wn * 64 + fn * 16 + (lane & 15);
      float bv = bf2f(bias[col]);
      for (int r = 0; r < 4; r++) {
        int row = m0 + wm * 64 + fm * 16 + g * 4 + r;
        float v = acc[fm][fn][r] + bv;
        if (RELU) v = fmaxf(v, 0.f);
        C[(size_t)row * N + col] = f2bf(v);
      }
    }
}

// ---------------- output store: bf16 ws -> d_out (dtype per flag) ----------------
__global__ __launch_bounds__(256) void store_k(const uint16_t* __restrict__ yb,
                                               void* __restrict__ out, int n,
                                               const uint32_t* __restrict__ flag) {
  const int isbf = (int)flag[0];
  float* of = (float*)out;
  uint16_t* ou = (uint16_t*)out;
  for (int i = blockIdx.x * 256 + threadIdx.x; i < n; i += gridDim.x * 256) {
    uint16_t v = yb[i];
    if (isbf) ou[i] = v; else of[i] = bf2f(v);
  }
}

extern "C" void kernel_launch(void* const* d_in, const int* in_sizes, int n_in,
                              void* d_out, int out_size, void* d_ws, size_t ws_size,
                              hipStream_t stream) {
  const void* de_x = d_in[0];
  const void* en_x = d_in[1];
  const void* mask = d_in[2];
  const void* Wq = d_in[3];
  const void* Wk = d_in[4];
  const void* Wv = d_in[5];
  const void* W1 = d_in[6];
  const void* b1 = d_in[7];
  const void* W2 = d_in[8];
  const void* b2 = d_in[9];

  uint16_t* ws = (uint16_t*)d_ws;
  const size_t M1 = (size_t)1 << 20;   // units of 2^20 bf16 elements (2 MB)
  uint32_t* flag = (uint32_t*)ws;              // unit 0: flag + small bufs
  uint16_t* b1c = ws + 1024;                   // 2048 elems
  uint16_t* b2c = ws + 4096;                   // 1024 elems
  uint16_t* Wtq = ws + 1 * M1;                 // [16][64][1024]
  uint16_t* Wtk = ws + 2 * M1;
  uint16_t* Wtv = ws + 3 * M1;
  uint16_t* W1t = ws + 4 * M1;                 // [2048][1024] (2 units)
  uint16_t* W2t = ws + 6 * M1;                 // [1024][2048] (2 units)
  uint16_t* de_c = ws + 8 * M1;                // [4096][1024] (4 units)
  uint16_t* en_c = ws + 12 * M1;               // (4 units)
  uint16_t* Qb  = ws + 16 * M1;                // [B,H,S,64] (4 units)
  uint16_t* Kb  = ws + 20 * M1;                // (4)
  uint16_t* Vtb = ws + 24 * M1;                // [B,H,64,S] (4)
  uint16_t* h1  = ws + 28 * M1;                // [4096][1024] (4)
  uint16_t* h2  = ws + 32 * M1;                // (4)  -> total 36 units = 72 MB
  uint16_t* ff1 = Qb;                          // reuse: [4096][2048] (8 units, Qb+Kb dead)
  uint16_t* yb  = Vtb;                         // reuse: [4096][1024] (4 units, Vtb dead)

  const int NX = 2 * 2048 * 1024;   // 4.19M elements
  dim3 blk(256);

  probe_k<<<1, 1, 0, stream>>>((const uint32_t*)mask, flag);
  cvt_k<<<2048, blk, 0, stream>>>(de_x, de_c, NX, flag);
  cvt_k<<<2048, blk, 0, stream>>>(en_x, en_c, NX, flag);
  cvt_k<<<8, blk, 0, stream>>>(b1, b1c, 2048, flag);
  cvt_k<<<4, blk, 0, stream>>>(b2, b2c, 1024, flag);
  // weight transposes -> bf16
  transpose_k<<<dim3(2, 32, 16), blk, 0, stream>>>(Wq, Wtq, 1024, 64, flag);
  transpose_k<<<dim3(2, 32, 16), blk, 0, stream>>>(Wk, Wtk, 1024, 64, flag);
  transpose_k<<<dim3(2, 32, 16), blk, 0, stream>>>(Wv, Wtv, 1024, 64, flag);
  transpose_k<<<dim3(64, 32, 1), blk, 0, stream>>>(W1, W1t, 1024, 2048, flag);
  transpose_k<<<dim3(32, 64, 1), blk, 0, stream>>>(W2, W2t, 2048, 1024, flag);
  // MHA1: q=k=v=de_x, causal
  proj_k<<<dim3(16, 48, 2), blk, 0, stream>>>(de_c, de_c, Wtq, Wtk, Wtv, Qb, Kb, Vtb);
  attn_k<1><<<dim3(32, 16, 2), blk, 0, stream>>>(Qb, Kb, Vtb, h1);
  // MHA2: q=k=en_x, v=h1, no mask
  proj_k<<<dim3(16, 48, 2), blk, 0, stream>>>(en_c, h1, Wtq, Wtk, Wtv, Qb, Kb, Vtb);
  attn_k<0><<<dim3(32, 16, 2), blk, 0, stream>>>(Qb, Kb, Vtb, h2);
  // FFN
  ff_k<1><<<dim3(32, 16), blk, 0, stream>>>(h2, W1t, b1c, ff1, 1024, 2048);
  ff_k<0><<<dim3(32, 8), blk, 0, stream>>>(ff1, W2t, b2c, yb, 2048, 1024);
  store_k<<<2048, blk, 0, stream>>>(yb, d_out, out_size, flag);
}

// Round 4
// 383.645 us; speedup vs baseline: 1.4179x; 1.4179x over previous
//
#include <hip/hip_runtime.h>
#include <stdint.h>

// DecoderLayer: B=2, S=2048, DIM=1024, H=16, DH=64, DFF=2048
// Round 4: 16x16x32 bf16 MFMA (__bf16 vectors), single-barrier double-buffered
// staging in proj/attn/ff, causal descending-qt load balance, Wq pre-scaled by
// 1/8, V epilogue LDS-transposed to coalesced stores.

#define DEV static __device__ __forceinline__

typedef __attribute__((ext_vector_type(8))) __bf16 bf16x8;           // MFMA A/B
typedef __attribute__((ext_vector_type(8))) unsigned short u16x8;    // staging
typedef __attribute__((ext_vector_type(4))) float f32x4;

DEV float bf2f(uint16_t u) { union { uint32_t u; float f; } v; v.u = ((uint32_t)u) << 16; return v.f; }
DEV uint16_t f2bf(float f) {
  union { float f; uint32_t u; } v; v.f = f;
  uint32_t r = v.u + 0x7fffu + ((v.u >> 16) & 1u);
  return (uint16_t)(r >> 16);
}

DEV bf16x8 asbf(u16x8 v) { return __builtin_bit_cast(bf16x8, v); }
DEV f32x4 mfma32(bf16x8 a, bf16x8 b, f32x4 c) {
  return __builtin_amdgcn_mfma_f32_16x16x32_bf16(a, b, c, 0, 0, 0);
}

// XOR swizzle: 16B slot s of row r lives at slot (s ^ (r&7)). Rows are 64 bf16 = 128B.
DEV int swz(int row, int slot) { return slot ^ (row & 7); }

// read an 8-element (16B) k-fragment from swizzled 64-col tile. slot = k0/8.
DEV bf16x8 frag8(const uint16_t* l, int row, int slot) {
  u16x8 v = *(const u16x8*)((const char*)l + row * 128 + (swz(row, slot) << 4));
  return asbf(v);
}

// ---------------- dtype probe ----------------
// f32 buffers: word1 of mask = bits(1.0f) -> low16 == 0. bf16: 0x3F803F80.
__global__ void probe_k(const uint32_t* __restrict__ mask, uint32_t* __restrict__ flag) {
  flag[0] = (mask[1] & 0xFFFFu) ? 1u : 0u;   // 1 = bf16, 0 = f32
}

// ---------------- ingest convert: (f32|bf16) -> bf16, 8 elems/thread ----------------
__global__ __launch_bounds__(256) void cvt_k(const void* __restrict__ src,
                                             uint16_t* __restrict__ dst, int n,
                                             const uint32_t* __restrict__ flag) {
  const int isbf = (int)flag[0];
  const int stride = gridDim.x * 256 * 8;
  for (int i = (blockIdx.x * 256 + threadIdx.x) * 8; i < n; i += stride) {
    if (isbf) {
      *(u16x8*)(dst + i) = *(const u16x8*)((const uint16_t*)src + i);
    } else {
      const float* sf = (const float*)src + i;
      u16x8 o;
      for (int j = 0; j < 8; j++) o[j] = f2bf(sf[j]);
      *(u16x8*)(dst + i) = o;
    }
  }
}

// ---------------- transpose+convert+scale: in[b][R][C] -> out[b][C][R] bf16 ----------------
__global__ __launch_bounds__(256) void transpose_k(const void* __restrict__ in_,
                                                   uint16_t* __restrict__ out, int R, int C,
                                                   float scale,
                                                   const uint32_t* __restrict__ flag) {
  __shared__ uint16_t t[32][33];
  const int isbf = (int)flag[0];
  const int b = blockIdx.z;
  const float* in_f = (const float*)in_ + (size_t)b * R * C;
  const uint16_t* in_u = (const uint16_t*)in_ + (size_t)b * R * C;
  out += (size_t)b * R * C;
  const int c0 = blockIdx.x * 32, r0 = blockIdx.y * 32;
  const int tx = threadIdx.x & 31, ty = threadIdx.x >> 5;
  for (int i = 0; i < 4; i++) {
    int r = ty + i * 8;
    size_t idx = (size_t)(r0 + r) * C + c0 + tx;
    uint16_t v;
    if (isbf) v = (scale == 1.0f) ? in_u[idx] : f2bf(bf2f(in_u[idx]) * scale);
    else      v = f2bf(in_f[idx] * scale);
    t[r][tx] = v;
  }
  __syncthreads();
  for (int i = 0; i < 4; i++) {
    int r = ty + i * 8;
    out[(size_t)(c0 + r) * R + r0 + tx] = t[tx][r];
  }
}

// ---------------- fused QKV projection (double-buffered) ----------------
// grid: (S/128, 3*16, B). proj = blockIdx.y>>4, h = blockIdx.y&15.
// Q,K out: [B,H,S,64]; V out transposed: [B,H,64,S] (via LDS-transpose epilogue)
__global__ __launch_bounds__(256) void proj_k(
    const uint16_t* __restrict__ A_qk, const uint16_t* __restrict__ A_v,
    const uint16_t* __restrict__ Wtq, const uint16_t* __restrict__ Wtk,
    const uint16_t* __restrict__ Wtv,
    uint16_t* __restrict__ Q, uint16_t* __restrict__ K, uint16_t* __restrict__ Vt) {
  __shared__ __attribute__((aligned(16))) uint16_t lA[2][128 * 64];
  __shared__ __attribute__((aligned(16))) uint16_t lB[2][64 * 64];
  const int tid = threadIdx.x, lane = tid & 63, wave = tid >> 6;
  const int g = lane >> 4;
  const int m0 = blockIdx.x * 128;
  const int h = blockIdx.y & 15, proj = blockIdx.y >> 4;
  const int b = blockIdx.z;
  const uint16_t* A = (proj == 2 ? A_v : A_qk) + (size_t)b * 2048 * 1024;
  const uint16_t* Bt = (proj == 0 ? Wtq : proj == 1 ? Wtk : Wtv) + (size_t)h * 64 * 1024;
  const int wm = wave >> 1, wn = wave & 1;
  f32x4 acc[4][2] = {};
  u16x8 ra[4], rb[2];
  const int cA = tid, rowA0 = cA >> 3, slotA = cA & 7;      // +i*256 -> +32 rows
  auto loadT = [&](int kt) {
    for (int i = 0; i < 4; i++)
      ra[i] = *(const u16x8*)(A + (size_t)(m0 + rowA0 + i * 32) * 1024 + kt + slotA * 8);
    for (int i = 0; i < 2; i++)
      rb[i] = *(const u16x8*)(Bt + (size_t)(rowA0 + i * 32) * 1024 + kt + slotA * 8);
  };
  auto writeT = [&](int buf) {
    for (int i = 0; i < 4; i++) {
      int row = rowA0 + i * 32;
      *(u16x8*)&lA[buf][(row * 8 + swz(row, slotA)) * 8] = ra[i];
    }
    for (int i = 0; i < 2; i++) {
      int row = rowA0 + i * 32;
      *(u16x8*)&lB[buf][(row * 8 + swz(row, slotA)) * 8] = rb[i];
    }
  };
  loadT(0);
  writeT(0);
  int cur = 0;
  for (int it = 0; it < 16; it++) {
    const int more = (it < 15);
    if (more) loadT((it + 1) * 64);
    __syncthreads();
    for (int kk = 0; kk < 2; kk++) {
      bf16x8 af[4], bfr[2];
      for (int fm = 0; fm < 4; fm++) af[fm] = frag8(lA[cur], wm * 64 + fm * 16 + (lane & 15), kk * 4 + g);
      for (int fn = 0; fn < 2; fn++) bfr[fn] = frag8(lB[cur], wn * 32 + fn * 16 + (lane & 15), kk * 4 + g);
      for (int fm = 0; fm < 4; fm++)
        for (int fn = 0; fn < 2; fn++)
          acc[fm][fn] = mfma32(af[fm], bfr[fn], acc[fm][fn]);
    }
    if (more) writeT(cur ^ 1);
    cur ^= 1;
  }
  const size_t bh = (size_t)(b * 16 + h);
  if (proj != 2) {
    uint16_t* outp = (proj == 0 ? Q : K);
    for (int fm = 0; fm < 4; fm++)
      for (int fn = 0; fn < 2; fn++)
        for (int r = 0; r < 4; r++) {
          int s = m0 + wm * 64 + fm * 16 + g * 4 + r;
          int e = wn * 32 + fn * 16 + (lane & 15);
          outp[(bh * 2048 + s) * 64 + e] = f2bf(acc[fm][fn][r]);
        }
  } else {
    // LDS-transpose epilogue: tv[64 e][128 s], then coalesced 16B row stores
    __syncthreads();
    uint16_t* tv = lA[0];
    for (int fm = 0; fm < 4; fm++)
      for (int fn = 0; fn < 2; fn++)
        for (int r = 0; r < 4; r++) {
          int s = wm * 64 + fm * 16 + g * 4 + r;
          int e = wn * 32 + fn * 16 + (lane & 15);
          tv[e * 128 + s] = f2bf(acc[fm][fn][r]);
        }
    __syncthreads();
    for (int e = tid >> 4; e < 64; e += 16) {
      int s = (tid & 15) * 8;
      *(u16x8*)(Vt + (bh * 64 + e) * 2048 + m0 + s) = *(const u16x8*)&tv[e * 128 + s];
    }
  }
}

// ---------------- flash attention (double-buffered) ----------------
// grid: (S/64, H, B). 4 waves x 16 q-rows. 64-key tiles. Q pre-scaled by 1/8.
template <int CAUSAL>
__global__ __launch_bounds__(256) void attn_k(const uint16_t* __restrict__ Q,
                                              const uint16_t* __restrict__ K,
                                              const uint16_t* __restrict__ Vt,
                                              uint16_t* __restrict__ O) {
  __shared__ __attribute__((aligned(16))) uint16_t lK[2][64 * 64];
  __shared__ __attribute__((aligned(16))) uint16_t lV[2][64 * 64];
  __shared__ __attribute__((aligned(16))) uint16_t lP[4][16 * 64];
  const int tid = threadIdx.x, lane = tid & 63, wave = tid >> 6;
  const int g = lane >> 4;
  const int qt = CAUSAL ? ((int)gridDim.x - 1 - (int)blockIdx.x) : (int)blockIdx.x;
  const int h = blockIdx.y, b = blockIdx.z;
  const size_t bh = (size_t)(b * 16 + h);
  const uint16_t* Qg = Q + bh * 2048 * 64;
  const uint16_t* Kg = K + bh * 2048 * 64;
  const uint16_t* Vg = Vt + bh * 64 * 2048;
  const int q0 = qt * 64;
  bf16x8 qf[2];
  {
    int row = q0 + wave * 16 + (lane & 15);
    for (int kk = 0; kk < 2; kk++)
      qf[kk] = asbf(*(const u16x8*)(Qg + (size_t)row * 64 + kk * 32 + g * 8));
  }
  uint16_t* lPw = lP[wave];
  f32x4 oacc[4] = {};
  float m_run[4], l_run[4];
  for (int r = 0; r < 4; r++) { m_run[r] = -INFINITY; l_run[r] = 0.f; }
  const int ktmax = CAUSAL ? qt : 31;
  u16x8 rk[2], rv[2];
  const int row0 = tid >> 3, slot0 = tid & 7;   // +i*32 rows
  auto loadKV = [&](int kt) {
    for (int i = 0; i < 2; i++) {
      int row = row0 + i * 32;
      rk[i] = *(const u16x8*)(Kg + (size_t)(kt * 64 + row) * 64 + slot0 * 8);
      rv[i] = *(const u16x8*)(Vg + (size_t)row * 2048 + kt * 64 + slot0 * 8);
    }
  };
  auto writeKV = [&](int buf) {
    for (int i = 0; i < 2; i++) {
      int row = row0 + i * 32;
      *(u16x8*)&lK[buf][(row * 8 + swz(row, slot0)) * 8] = rk[i];
      *(u16x8*)&lV[buf][(row * 8 + swz(row, slot0)) * 8] = rv[i];
    }
  };
  loadKV(0);
  writeKV(0);
  int cur = 0;
  for (int kt = 0; kt <= ktmax; kt++) {
    const int more = (kt < ktmax);
    if (more) loadKV(kt + 1);
    __syncthreads();
    // QK^T
    f32x4 s[4] = {};
    for (int kk = 0; kk < 2; kk++)
      for (int nf = 0; nf < 4; nf++)
        s[nf] = mfma32(qf[kk], frag8(lK[cur], nf * 16 + (lane & 15), kk * 4 + g), s[nf]);
    // online softmax
    float pm[4][4], rmax[4];
    for (int r = 0; r < 4; r++) rmax[r] = -INFINITY;
    for (int nf = 0; nf < 4; nf++)
      for (int r = 0; r < 4; r++) {
        float v = s[nf][r];
        if (CAUSAL && kt == qt) {
          int qloc = wave * 16 + g * 4 + r;
          int kloc = nf * 16 + (lane & 15);
          if (kloc > qloc) v = -1e9f;
        }
        pm[nf][r] = v;
        rmax[r] = fmaxf(rmax[r], v);
      }
    for (int m = 1; m < 16; m <<= 1)
      for (int r = 0; r < 4; r++) rmax[r] = fmaxf(rmax[r], __shfl_xor(rmax[r], m));
    float alpha[4], rsum[4];
    for (int r = 0; r < 4; r++) {
      float mn = fmaxf(m_run[r], rmax[r]);
      alpha[r] = __expf(m_run[r] - mn);
      m_run[r] = mn;
      rsum[r] = 0.f;
    }
    for (int nf = 0; nf < 4; nf++)
      for (int r = 0; r < 4; r++) {
        float p = __expf(pm[nf][r] - m_run[r]);
        rsum[r] += p;
        int row = g * 4 + r;             // q-row 0..15
        int col = nf * 16 + (lane & 15); // key 0..63
        *(uint16_t*)((char*)lPw + row * 128 + (swz(row, col >> 3) << 4) + ((col & 7) << 1)) = f2bf(p);
      }
    for (int m = 1; m < 16; m <<= 1)
      for (int r = 0; r < 4; r++) rsum[r] += __shfl_xor(rsum[r], m);
    for (int r = 0; r < 4; r++) l_run[r] = l_run[r] * alpha[r] + rsum[r];
    for (int df = 0; df < 4; df++) {
      f32x4 t = oacc[df];
      for (int r = 0; r < 4; r++) t[r] *= alpha[r];
      oacc[df] = t;
    }
    // PV
    for (int kk = 0; kk < 2; kk++) {
      bf16x8 pa = frag8(lPw, lane & 15, kk * 4 + g);
      for (int df = 0; df < 4; df++)
        oacc[df] = mfma32(pa, frag8(lV[cur], df * 16 + (lane & 15), kk * 4 + g), oacc[df]);
    }
    if (more) writeKV(cur ^ 1);
    cur ^= 1;
  }
  for (int df = 0; df < 4; df++)
    for (int r = 0; r < 4; r++) {
      int srow = q0 + wave * 16 + g * 4 + r;
      int e = df * 16 + (lane & 15);
      O[((size_t)b * 2048 + srow) * 1024 + h * 64 + e] = f2bf(oacc[df][r] / l_run[r]);
    }
}

// ---------------- FFN GEMM: C[M,N] = A[M,K] @ Bt[N,K]^T (+bias, relu), dbuf ----------------
template <int RELU>
__global__ __launch_bounds__(256) void ff_k(const uint16_t* __restrict__ A,
                                            const uint16_t* __restrict__ Bt,
                                            const uint16_t* __restrict__ bias,
                                            uint16_t* __restrict__ C, int Kdim, int N) {
  __shared__ __attribute__((aligned(16))) uint16_t lA[2][128 * 64];
  __shared__ __attribute__((aligned(16))) uint16_t lB[2][128 * 64];
  const int tid = threadIdx.x, lane = tid & 63, wave = tid >> 6;
  const int g = lane >> 4;
  const int m0 = blockIdx.x * 128, n0 = blockIdx.y * 128;
  const int wm = wave >> 1, wn = wave & 1;
  f32x4 acc[4][4] = {};
  u16x8 ra[4], rb[4];
  const int row0 = tid >> 3, slot0 = tid & 7;   // +i*32 rows
  auto loadT = [&](int kt) {
    for (int i = 0; i < 4; i++) {
      int row = row0 + i * 32;
      ra[i] = *(const u16x8*)(A + (size_t)(m0 + row) * Kdim + kt + slot0 * 8);
      rb[i] = *(const u16x8*)(Bt + (size_t)(n0 + row) * Kdim + kt + slot0 * 8);
    }
  };
  auto writeT = [&](int buf) {
    for (int i = 0; i < 4; i++) {
      int row = row0 + i * 32;
      *(u16x8*)&lA[buf][(row * 8 + swz(row, slot0)) * 8] = ra[i];
      *(u16x8*)&lB[buf][(row * 8 + swz(row, slot0)) * 8] = rb[i];
    }
  };
  loadT(0);
  writeT(0);
  int cur = 0;
  const int nit = Kdim >> 6;
  for (int it = 0; it < nit; it++) {
    const int more = (it < nit - 1);
    if (more) loadT((it + 1) * 64);
    __syncthreads();
    for (int kk = 0; kk < 2; kk++) {
      bf16x8 af[4], bfr[4];
      for (int fm = 0; fm < 4; fm++) af[fm] = frag8(lA[cur], wm * 64 + fm * 16 + (lane & 15), kk * 4 + g);
      for (int fn = 0; fn < 4; fn++) bfr[fn] = frag8(lB[cur], wn * 64 + fn * 16 + (lane & 15), kk * 4 + g);
      for (int fm = 0; fm < 4; fm++)
        for (int fn = 0; fn < 4; fn++)
          acc[fm][fn] = mfma32(af[fm], bfr[fn], acc[fm][fn]);
    }
    if (more) writeT(cur ^ 1);
    cur ^= 1;
  }
  for (int fm = 0; fm < 4; fm++)
    for (int fn = 0; fn < 4; fn++) {
      int col = n0 + wn * 64 + fn * 16 + (lane & 15);
      float bv = bf2f(bias[col]);
      for (int r = 0; r < 4; r++) {
        int row = m0 + wm * 64 + fm * 16 + g * 4 + r;
        float v = acc[fm][fn][r] + bv;
        if (RELU) v = fmaxf(v, 0.f);
        C[(size_t)row * N + col] = f2bf(v);
      }
    }
}

// ---------------- output store: bf16 ws -> d_out (dtype per flag) ----------------
__global__ __launch_bounds__(256) void store_k(const uint16_t* __restrict__ yb,
                                               void* __restrict__ out, int n,
                                               const uint32_t* __restrict__ flag) {
  const int isbf = (int)flag[0];
  const int stride = gridDim.x * 256 * 8;
  for (int i = (blockIdx.x * 256 + threadIdx.x) * 8; i < n; i += stride) {
    u16x8 v = *(const u16x8*)(yb + i);
    if (isbf) {
      *(u16x8*)((uint16_t*)out + i) = v;
    } else {
      float* of = (float*)out + i;
      for (int j = 0; j < 8; j++) of[j] = bf2f(v[j]);
    }
  }
}

extern "C" void kernel_launch(void* const* d_in, const int* in_sizes, int n_in,
                              void* d_out, int out_size, void* d_ws, size_t ws_size,
                              hipStream_t stream) {
  const void* de_x = d_in[0];
  const void* en_x = d_in[1];
  const void* mask = d_in[2];
  const void* Wq = d_in[3];
  const void* Wk = d_in[4];
  const void* Wv = d_in[5];
  const void* W1 = d_in[6];
  const void* b1 = d_in[7];
  const void* W2 = d_in[8];
  const void* b2 = d_in[9];

  uint16_t* ws = (uint16_t*)d_ws;
  const size_t M1 = (size_t)1 << 20;   // units of 2^20 bf16 elements (2 MB)
  uint32_t* flag = (uint32_t*)ws;
  uint16_t* b1c = ws + 1024;
  uint16_t* b2c = ws + 4096;
  uint16_t* Wtq = ws + 1 * M1;                 // [16][64][1024] (pre-scaled 1/8)
  uint16_t* Wtk = ws + 2 * M1;
  uint16_t* Wtv = ws + 3 * M1;
  uint16_t* W1t = ws + 4 * M1;                 // [2048][1024]
  uint16_t* W2t = ws + 6 * M1;                 // [1024][2048]
  uint16_t* de_c = ws + 8 * M1;                // [4096][1024]
  uint16_t* en_c = ws + 12 * M1;
  uint16_t* Qb  = ws + 16 * M1;                // [B,H,S,64]
  uint16_t* Kb  = ws + 20 * M1;
  uint16_t* Vtb = ws + 24 * M1;                // [B,H,64,S]
  uint16_t* h1  = ws + 28 * M1;
  uint16_t* h2  = ws + 32 * M1;                // total 36 units = 72 MB
  uint16_t* ff1 = Qb;                          // reuse (Qb/Kb dead): [4096][2048]
  uint16_t* yb  = Vtb;                         // reuse: [4096][1024]

  const int NX = 2 * 2048 * 1024;
  dim3 blk(256);

  probe_k<<<1, 1, 0, stream>>>((const uint32_t*)mask, flag);
  cvt_k<<<2048, blk, 0, stream>>>(de_x, de_c, NX, flag);
  cvt_k<<<2048, blk, 0, stream>>>(en_x, en_c, NX, flag);
  cvt_k<<<1, blk, 0, stream>>>(b1, b1c, 2048, flag);
  cvt_k<<<1, blk, 0, stream>>>(b2, b2c, 1024, flag);
  transpose_k<<<dim3(2, 32, 16), blk, 0, stream>>>(Wq, Wtq, 1024, 64, 0.125f, flag);
  transpose_k<<<dim3(2, 32, 16), blk, 0, stream>>>(Wk, Wtk, 1024, 64, 1.0f, flag);
  transpose_k<<<dim3(2, 32, 16), blk, 0, stream>>>(Wv, Wtv, 1024, 64, 1.0f, flag);
  transpose_k<<<dim3(64, 32, 1), blk, 0, stream>>>(W1, W1t, 1024, 2048, 1.0f, flag);
  transpose_k<<<dim3(32, 64, 1), blk, 0, stream>>>(W2, W2t, 2048, 1024, 1.0f, flag);
  // MHA1: q=k=v=de_x, causal
  proj_k<<<dim3(16, 48, 2), blk, 0, stream>>>(de_c, de_c, Wtq, Wtk, Wtv, Qb, Kb, Vtb);
  attn_k<1><<<dim3(32, 16, 2), blk, 0, stream>>>(Qb, Kb, Vtb, h1);
  // MHA2: q=k=en_x, v=h1, no mask
  proj_k<<<dim3(16, 48, 2), blk, 0, stream>>>(en_c, h1, Wtq, Wtk, Wtv, Qb, Kb, Vtb);
  attn_k<0><<<dim3(32, 16, 2), blk, 0, stream>>>(Qb, Kb, Vtb, h2);
  // FFN
  ff_k<1><<<dim3(32, 16), blk, 0, stream>>>(h2, W1t, b1c, ff1, 1024, 2048);
  ff_k<0><<<dim3(32, 8), blk, 0, stream>>>(ff1, W2t, b2c, yb, 2048, 1024);
  store_k<<<2048, blk, 0, stream>>>(yb, d_out, out_size, flag);
}

// Round 5
// 316.198 us; speedup vs baseline: 1.7204x; 1.2133x over previous
//
#include <hip/hip_runtime.h>
#include <stdint.h>

// DecoderLayer: B=2, S=2048, DIM=1024, H=16, DH=64, DFF=2048
// Round 5: attention softmax in log2 domain (Wq pre-scaled by 0.125*log2e),
// defer-max (THR=8), hw bf16 cvt for P, XOR-incremental P addresses, and
// causal load-balance via paired q-tiles (block x does qt=x and qt=31-x).

#define DEV static __device__ __forceinline__

typedef __attribute__((ext_vector_type(8))) __bf16 bf16x8;           // MFMA A/B
typedef __attribute__((ext_vector_type(8))) unsigned short u16x8;    // staging
typedef __attribute__((ext_vector_type(4))) float f32x4;

DEV float bf2f(uint16_t u) { union { uint32_t u; float f; } v; v.u = ((uint32_t)u) << 16; return v.f; }
DEV uint16_t f2bf(float f) {
  union { float f; uint32_t u; } v; v.f = f;
  uint32_t r = v.u + 0x7fffu + ((v.u >> 16) & 1u);
  return (uint16_t)(r >> 16);
}
DEV uint16_t f2bf_hw(float f) { return __builtin_bit_cast(unsigned short, (__bf16)f); }

DEV bf16x8 asbf(u16x8 v) { return __builtin_bit_cast(bf16x8, v); }
DEV f32x4 mfma32(bf16x8 a, bf16x8 b, f32x4 c) {
  return __builtin_amdgcn_mfma_f32_16x16x32_bf16(a, b, c, 0, 0, 0);
}

// XOR swizzle: 16B slot s of row r lives at slot (s ^ (r&7)). Rows are 64 bf16 = 128B.
DEV int swz(int row, int slot) { return slot ^ (row & 7); }

// read an 8-element (16B) k-fragment from swizzled 64-col tile. slot = k0/8.
DEV bf16x8 frag8(const uint16_t* l, int row, int slot) {
  u16x8 v = *(const u16x8*)((const char*)l + row * 128 + (swz(row, slot) << 4));
  return asbf(v);
}

// ---------------- dtype probe ----------------
__global__ void probe_k(const uint32_t* __restrict__ mask, uint32_t* __restrict__ flag) {
  flag[0] = (mask[1] & 0xFFFFu) ? 1u : 0u;   // 1 = bf16, 0 = f32
}

// ---------------- ingest convert ----------------
__global__ __launch_bounds__(256) void cvt_k(const void* __restrict__ src,
                                             uint16_t* __restrict__ dst, int n,
                                             const uint32_t* __restrict__ flag) {
  const int isbf = (int)flag[0];
  const int stride = gridDim.x * 256 * 8;
  for (int i = (blockIdx.x * 256 + threadIdx.x) * 8; i < n; i += stride) {
    if (isbf) {
      *(u16x8*)(dst + i) = *(const u16x8*)((const uint16_t*)src + i);
    } else {
      const float* sf = (const float*)src + i;
      u16x8 o;
      for (int j = 0; j < 8; j++) o[j] = f2bf(sf[j]);
      *(u16x8*)(dst + i) = o;
    }
  }
}

// ---------------- transpose+convert+scale: in[b][R][C] -> out[b][C][R] bf16 ----------------
__global__ __launch_bounds__(256) void transpose_k(const void* __restrict__ in_,
                                                   uint16_t* __restrict__ out, int R, int C,
                                                   float scale,
                                                   const uint32_t* __restrict__ flag) {
  __shared__ uint16_t t[32][33];
  const int isbf = (int)flag[0];
  const int b = blockIdx.z;
  const float* in_f = (const float*)in_ + (size_t)b * R * C;
  const uint16_t* in_u = (const uint16_t*)in_ + (size_t)b * R * C;
  out += (size_t)b * R * C;
  const int c0 = blockIdx.x * 32, r0 = blockIdx.y * 32;
  const int tx = threadIdx.x & 31, ty = threadIdx.x >> 5;
  for (int i = 0; i < 4; i++) {
    int r = ty + i * 8;
    size_t idx = (size_t)(r0 + r) * C + c0 + tx;
    uint16_t v;
    if (isbf) v = (scale == 1.0f) ? in_u[idx] : f2bf(bf2f(in_u[idx]) * scale);
    else      v = f2bf(in_f[idx] * scale);
    t[r][tx] = v;
  }
  __syncthreads();
  for (int i = 0; i < 4; i++) {
    int r = ty + i * 8;
    out[(size_t)(c0 + r) * R + r0 + tx] = t[tx][r];
  }
}

// ---------------- fused QKV projection (double-buffered) ----------------
__global__ __launch_bounds__(256) void proj_k(
    const uint16_t* __restrict__ A_qk, const uint16_t* __restrict__ A_v,
    const uint16_t* __restrict__ Wtq, const uint16_t* __restrict__ Wtk,
    const uint16_t* __restrict__ Wtv,
    uint16_t* __restrict__ Q, uint16_t* __restrict__ K, uint16_t* __restrict__ Vt) {
  __shared__ __attribute__((aligned(16))) uint16_t lA[2][128 * 64];
  __shared__ __attribute__((aligned(16))) uint16_t lB[2][64 * 64];
  const int tid = threadIdx.x, lane = tid & 63, wave = tid >> 6;
  const int g = lane >> 4;
  const int m0 = blockIdx.x * 128;
  const int h = blockIdx.y & 15, proj = blockIdx.y >> 4;
  const int b = blockIdx.z;
  const uint16_t* A = (proj == 2 ? A_v : A_qk) + (size_t)b * 2048 * 1024;
  const uint16_t* Bt = (proj == 0 ? Wtq : proj == 1 ? Wtk : Wtv) + (size_t)h * 64 * 1024;
  const int wm = wave >> 1, wn = wave & 1;
  f32x4 acc[4][2] = {};
  u16x8 ra[4], rb[2];
  const int rowA0 = tid >> 3, slotA = tid & 7;
  auto loadT = [&](int kt) {
    for (int i = 0; i < 4; i++)
      ra[i] = *(const u16x8*)(A + (size_t)(m0 + rowA0 + i * 32) * 1024 + kt + slotA * 8);
    for (int i = 0; i < 2; i++)
      rb[i] = *(const u16x8*)(Bt + (size_t)(rowA0 + i * 32) * 1024 + kt + slotA * 8);
  };
  auto writeT = [&](int buf) {
    for (int i = 0; i < 4; i++) {
      int row = rowA0 + i * 32;
      *(u16x8*)&lA[buf][(row * 8 + swz(row, slotA)) * 8] = ra[i];
    }
    for (int i = 0; i < 2; i++) {
      int row = rowA0 + i * 32;
      *(u16x8*)&lB[buf][(row * 8 + swz(row, slotA)) * 8] = rb[i];
    }
  };
  loadT(0);
  writeT(0);
  int cur = 0;
  for (int it = 0; it < 16; it++) {
    const int more = (it < 15);
    if (more) loadT((it + 1) * 64);
    __syncthreads();
    for (int kk = 0; kk < 2; kk++) {
      bf16x8 af[4], bfr[2];
      for (int fm = 0; fm < 4; fm++) af[fm] = frag8(lA[cur], wm * 64 + fm * 16 + (lane & 15), kk * 4 + g);
      for (int fn = 0; fn < 2; fn++) bfr[fn] = frag8(lB[cur], wn * 32 + fn * 16 + (lane & 15), kk * 4 + g);
      for (int fm = 0; fm < 4; fm++)
        for (int fn = 0; fn < 2; fn++)
          acc[fm][fn] = mfma32(af[fm], bfr[fn], acc[fm][fn]);
    }
    if (more) writeT(cur ^ 1);
    cur ^= 1;
  }
  const size_t bh = (size_t)(b * 16 + h);
  if (proj != 2) {
    uint16_t* outp = (proj == 0 ? Q : K);
    for (int fm = 0; fm < 4; fm++)
      for (int fn = 0; fn < 2; fn++)
        for (int r = 0; r < 4; r++) {
          int s = m0 + wm * 64 + fm * 16 + g * 4 + r;
          int e = wn * 32 + fn * 16 + (lane & 15);
          outp[(bh * 2048 + s) * 64 + e] = f2bf(acc[fm][fn][r]);
        }
  } else {
    __syncthreads();
    uint16_t* tv = lA[0];
    for (int fm = 0; fm < 4; fm++)
      for (int fn = 0; fn < 2; fn++)
        for (int r = 0; r < 4; r++) {
          int s = wm * 64 + fm * 16 + g * 4 + r;
          int e = wn * 32 + fn * 16 + (lane & 15);
          tv[e * 128 + s] = f2bf(acc[fm][fn][r]);
        }
    __syncthreads();
    for (int e = tid >> 4; e < 64; e += 16) {
      int s = (tid & 15) * 8;
      *(u16x8*)(Vt + (bh * 64 + e) * 2048 + m0 + s) = *(const u16x8*)&tv[e * 128 + s];
    }
  }
}

// ---------------- flash attention (log2-domain, defer-max, dbuf) ----------------
// Q pre-scaled by 0.125*log2e. CAUSAL: grid.x=16, passes qt={x, 31-x} (33 tiles
// per block, uniform). Non-causal: grid.x=32, 1 pass.
template <int CAUSAL>
__global__ __launch_bounds__(256) void attn_k(const uint16_t* __restrict__ Q,
                                              const uint16_t* __restrict__ K,
                                              const uint16_t* __restrict__ Vt,
                                              uint16_t* __restrict__ O) {
  __shared__ __attribute__((aligned(16))) uint16_t lK[2][64 * 64];
  __shared__ __attribute__((aligned(16))) uint16_t lV[2][64 * 64];
  __shared__ __attribute__((aligned(16))) uint16_t lP[4][16 * 64];
  const int tid = threadIdx.x, lane = tid & 63, wave = tid >> 6;
  const int g = lane >> 4;
  const int h = blockIdx.y, b = blockIdx.z;
  const size_t bh = (size_t)(b * 16 + h);
  const uint16_t* Qg = Q + bh * 2048 * 64;
  const uint16_t* Kg = K + bh * 2048 * 64;
  const uint16_t* Vg = Vt + bh * 64 * 2048;
  uint16_t* lPw = lP[wave];
  // P-store base addresses: addr(r,nf) = pbase[r] ^ (nf<<5)
  uint32_t pbase[4];
  for (int r = 0; r < 4; r++) {
    int row = g * 4 + r;
    pbase[r] = row * 128 + (((((lane & 15) >> 3)) ^ (row & 7)) << 4) + ((lane & 7) << 1);
  }
  u16x8 rk[2], rv[2];
  const int row0 = tid >> 3, slot0 = tid & 7;
  auto loadKV = [&](int kt) {
    for (int i = 0; i < 2; i++) {
      int row = row0 + i * 32;
      rk[i] = *(const u16x8*)(Kg + (size_t)(kt * 64 + row) * 64 + slot0 * 8);
      rv[i] = *(const u16x8*)(Vg + (size_t)row * 2048 + kt * 64 + slot0 * 8);
    }
  };
  auto writeKV = [&](int buf) {
    for (int i = 0; i < 2; i++) {
      int row = row0 + i * 32;
      *(u16x8*)&lK[buf][(row * 8 + swz(row, slot0)) * 8] = rk[i];
      *(u16x8*)&lV[buf][(row * 8 + swz(row, slot0)) * 8] = rv[i];
    }
  };
  const int npass = CAUSAL ? 2 : 1;
  for (int pass = 0; pass < npass; pass++) {
    const int qt = CAUSAL ? (pass ? 31 - (int)blockIdx.x : (int)blockIdx.x) : (int)blockIdx.x;
    const int q0 = qt * 64;
    bf16x8 qf[2];
    {
      int row = q0 + wave * 16 + (lane & 15);
      for (int kk = 0; kk < 2; kk++)
        qf[kk] = asbf(*(const u16x8*)(Qg + (size_t)row * 64 + kk * 32 + g * 8));
    }
    f32x4 oacc[4] = {};
    float m_run[4], l_run[4];
    for (int r = 0; r < 4; r++) { m_run[r] = -INFINITY; l_run[r] = 0.f; }
    const int ktmax = CAUSAL ? qt : 31;
    loadKV(0);
    __syncthreads();   // protect prev pass's last-tile reads before overwrite
    writeKV(0);
    int cur = 0;
    for (int kt = 0; kt <= ktmax; kt++) {
      const int more = (kt < ktmax);
      if (more) loadKV(kt + 1);
      __syncthreads();
      // QK^T (log2 domain)
      f32x4 s[4] = {};
      for (int kk = 0; kk < 2; kk++)
        for (int nf = 0; nf < 4; nf++)
          s[nf] = mfma32(qf[kk], frag8(lK[cur], nf * 16 + (lane & 15), kk * 4 + g), s[nf]);
      float pm[4][4];
      for (int nf = 0; nf < 4; nf++)
        for (int r = 0; r < 4; r++) {
          float v = s[nf][r];
          if (CAUSAL && kt == qt) {
            int qloc = wave * 16 + g * 4 + r;
            int kloc = nf * 16 + (lane & 15);
            if (kloc > qloc) v = -1e9f;
          }
          pm[nf][r] = v;
        }
      // local row max; defer-max fast path
      float rloc[4];
      for (int r = 0; r < 4; r++)
        rloc[r] = fmaxf(fmaxf(pm[0][r], pm[1][r]), fmaxf(pm[2][r], pm[3][r]));
      bool ok = true;
      for (int r = 0; r < 4; r++) ok = ok && (rloc[r] <= m_run[r] + 8.0f);
      if (!__all(ok)) {
        float rmax[4];
        for (int r = 0; r < 4; r++) rmax[r] = rloc[r];
        for (int m = 1; m < 16; m <<= 1)
          for (int r = 0; r < 4; r++) rmax[r] = fmaxf(rmax[r], __shfl_xor(rmax[r], m));
        for (int r = 0; r < 4; r++) {
          float mn = fmaxf(m_run[r], rmax[r]);
          float alpha = exp2f(m_run[r] - mn);
          m_run[r] = mn;
          l_run[r] *= alpha;
          for (int df = 0; df < 4; df++) oacc[df][r] *= alpha;
        }
      }
      float rsum[4] = {0.f, 0.f, 0.f, 0.f};
      for (int nf = 0; nf < 4; nf++)
        for (int r = 0; r < 4; r++) {
          float p = exp2f(pm[nf][r] - m_run[r]);
          rsum[r] += p;
          *(uint16_t*)((char*)lPw + (pbase[r] ^ (nf << 5))) = f2bf_hw(p);
        }
      for (int m = 1; m < 16; m <<= 1)
        for (int r = 0; r < 4; r++) rsum[r] += __shfl_xor(rsum[r], m);
      for (int r = 0; r < 4; r++) l_run[r] += rsum[r];
      // PV
      for (int kk = 0; kk < 2; kk++) {
        bf16x8 pa = frag8(lPw, lane & 15, kk * 4 + g);
        for (int df = 0; df < 4; df++)
          oacc[df] = mfma32(pa, frag8(lV[cur], df * 16 + (lane & 15), kk * 4 + g), oacc[df]);
      }
      if (more) writeKV(cur ^ 1);
      cur ^= 1;
    }
    float inv[4];
    for (int r = 0; r < 4; r++) inv[r] = 1.0f / l_run[r];
    for (int df = 0; df < 4; df++)
      for (int r = 0; r < 4; r++) {
        int srow = q0 + wave * 16 + g * 4 + r;
        int e = df * 16 + (lane & 15);
        O[((size_t)b * 2048 + srow) * 1024 + h * 64 + e] = f2bf(oacc[df][r] * inv[r]);
      }
  }
}

// ---------------- FFN GEMM: C[M,N] = A[M,K] @ Bt[N,K]^T (+bias, relu), dbuf ----------------
template <int RELU>
__global__ __launch_bounds__(256) void ff_k(const uint16_t* __restrict__ A,
                                            const uint16_t* __restrict__ Bt,
                                            const uint16_t* __restrict__ bias,
                                            uint16_t* __restrict__ C, int Kdim, int N) {
  __shared__ __attribute__((aligned(16))) uint16_t lA[2][128 * 64];
  __shared__ __attribute__((aligned(16))) uint16_t lB[2][128 * 64];
  const int tid = threadIdx.x, lane = tid & 63, wave = tid >> 6;
  const int g = lane >> 4;
  const int m0 = blockIdx.x * 128, n0 = blockIdx.y * 128;
  const int wm = wave >> 1, wn = wave & 1;
  f32x4 acc[4][4] = {};
  u16x8 ra[4], rb[4];
  const int row0 = tid >> 3, slot0 = tid & 7;
  auto loadT = [&](int kt) {
    for (int i = 0; i < 4; i++) {
      int row = row0 + i * 32;
      ra[i] = *(const u16x8*)(A + (size_t)(m0 + row) * Kdim + kt + slot0 * 8);
      rb[i] = *(const u16x8*)(Bt + (size_t)(n0 + row) * Kdim + kt + slot0 * 8);
    }
  };
  auto writeT = [&](int buf) {
    for (int i = 0; i < 4; i++) {
      int row = row0 + i * 32;
      *(u16x8*)&lA[buf][(row * 8 + swz(row, slot0)) * 8] = ra[i];
      *(u16x8*)&lB[buf][(row * 8 + swz(row, slot0)) * 8] = rb[i];
    }
  };
  loadT(0);
  writeT(0);
  int cur = 0;
  const int nit = Kdim >> 6;
  for (int it = 0; it < nit; it++) {
    const int more = (it < nit - 1);
    if (more) loadT((it + 1) * 64);
    __syncthreads();
    for (int kk = 0; kk < 2; kk++) {
      bf16x8 af[4], bfr[4];
      for (int fm = 0; fm < 4; fm++) af[fm] = frag8(lA[cur], wm * 64 + fm * 16 + (lane & 15), kk * 4 + g);
      for (int fn = 0; fn < 4; fn++) bfr[fn] = frag8(lB[cur], wn * 64 + fn * 16 + (lane & 15), kk * 4 + g);
      for (int fm = 0; fm < 4; fm++)
        for (int fn = 0; fn < 4; fn++)
          acc[fm][fn] = mfma32(af[fm], bfr[fn], acc[fm][fn]);
    }
    if (more) writeT(cur ^ 1);
    cur ^= 1;
  }
  for (int fm = 0; fm < 4; fm++)
    for (int fn = 0; fn < 4; fn++) {
      int col = n0 + wn * 64 + fn * 16 + (lane & 15);
      float bv = bf2f(bias[col]);
      for (int r = 0; r < 4; r++) {
        int row = m0 + wm * 64 + fm * 16 + g * 4 + r;
        float v = acc[fm][fn][r] + bv;
        if (RELU) v = fmaxf(v, 0.f);
        C[(size_t)row * N + col] = f2bf(v);
      }
    }
}

// ---------------- output store ----------------
__global__ __launch_bounds__(256) void store_k(const uint16_t* __restrict__ yb,
                                               void* __restrict__ out, int n,
                                               const uint32_t* __restrict__ flag) {
  const int isbf = (int)flag[0];
  const int stride = gridDim.x * 256 * 8;
  for (int i = (blockIdx.x * 256 + threadIdx.x) * 8; i < n; i += stride) {
    u16x8 v = *(const u16x8*)(yb + i);
    if (isbf) {
      *(u16x8*)((uint16_t*)out + i) = v;
    } else {
      float* of = (float*)out + i;
      for (int j = 0; j < 8; j++) of[j] = bf2f(v[j]);
    }
  }
}

extern "C" void kernel_launch(void* const* d_in, const int* in_sizes, int n_in,
                              void* d_out, int out_size, void* d_ws, size_t ws_size,
                              hipStream_t stream) {
  const void* de_x = d_in[0];
  const void* en_x = d_in[1];
  const void* mask = d_in[2];
  const void* Wq = d_in[3];
  const void* Wk = d_in[4];
  const void* Wv = d_in[5];
  const void* W1 = d_in[6];
  const void* b1 = d_in[7];
  const void* W2 = d_in[8];
  const void* b2 = d_in[9];

  uint16_t* ws = (uint16_t*)d_ws;
  const size_t M1 = (size_t)1 << 20;
  uint32_t* flag = (uint32_t*)ws;
  uint16_t* b1c = ws + 1024;
  uint16_t* b2c = ws + 4096;
  uint16_t* Wtq = ws + 1 * M1;                 // [16][64][1024], scaled 0.125*log2e
  uint16_t* Wtk = ws + 2 * M1;
  uint16_t* Wtv = ws + 3 * M1;
  uint16_t* W1t = ws + 4 * M1;                 // [2048][1024]
  uint16_t* W2t = ws + 6 * M1;                 // [1024][2048]
  uint16_t* de_c = ws + 8 * M1;                // [4096][1024]
  uint16_t* en_c = ws + 12 * M1;
  uint16_t* Qb  = ws + 16 * M1;                // [B,H,S,64]
  uint16_t* Kb  = ws + 20 * M1;
  uint16_t* Vtb = ws + 24 * M1;                // [B,H,64,S]
  uint16_t* h1  = ws + 28 * M1;
  uint16_t* h2  = ws + 32 * M1;
  uint16_t* ff1 = Qb;                          // reuse
  uint16_t* yb  = Vtb;                         // reuse

  const int NX = 2 * 2048 * 1024;
  dim3 blk(256);

  probe_k<<<1, 1, 0, stream>>>((const uint32_t*)mask, flag);
  cvt_k<<<2048, blk, 0, stream>>>(de_x, de_c, NX, flag);
  cvt_k<<<2048, blk, 0, stream>>>(en_x, en_c, NX, flag);
  cvt_k<<<1, blk, 0, stream>>>(b1, b1c, 2048, flag);
  cvt_k<<<1, blk, 0, stream>>>(b2, b2c, 1024, flag);
  transpose_k<<<dim3(2, 32, 16), blk, 0, stream>>>(Wq, Wtq, 1024, 64, 0.180336880f, flag); // 0.125*log2(e)
  transpose_k<<<dim3(2, 32, 16), blk, 0, stream>>>(Wk, Wtk, 1024, 64, 1.0f, flag);
  transpose_k<<<dim3(2, 32, 16), blk, 0, stream>>>(Wv, Wtv, 1024, 64, 1.0f, flag);
  transpose_k<<<dim3(64, 32, 1), blk, 0, stream>>>(W1, W1t, 1024, 2048, 1.0f, flag);
  transpose_k<<<dim3(32, 64, 1), blk, 0, stream>>>(W2, W2t, 2048, 1024, 1.0f, flag);
  // MHA1: q=k=v=de_x, causal (paired q-tiles)
  proj_k<<<dim3(16, 48, 2), blk, 0, stream>>>(de_c, de_c, Wtq, Wtk, Wtv, Qb, Kb, Vtb);
  attn_k<1><<<dim3(16, 16, 2), blk, 0, stream>>>(Qb, Kb, Vtb, h1);
  // MHA2: q=k=en_x, v=h1, no mask
  proj_k<<<dim3(16, 48, 2), blk, 0, stream>>>(en_c, h1, Wtq, Wtk, Wtv, Qb, Kb, Vtb);
  attn_k<0><<<dim3(32, 16, 2), blk, 0, stream>>>(Qb, Kb, Vtb, h2);
  // FFN
  ff_k<1><<<dim3(32, 16), blk, 0, stream>>>(h2, W1t, b1c, ff1, 1024, 2048);
  ff_k<0><<<dim3(32, 8), blk, 0, stream>>>(ff1, W2t, b2c, yb, 2048, 1024);
  store_k<<<2048, blk, 0, stream>>>(yb, d_out, out_size, flag);
}

// Round 6
// 283.693 us; speedup vs baseline: 1.9175x; 1.1146x over previous
//
#include <hip/hip_runtime.h>
#include <stdint.h>

// DecoderLayer: B=2, S=2048, DIM=1024, H=16, DH=64, DFF=2048
// Round 6: attn occupancy 24KB LDS (single K/V buffer, 2-barrier + reg
// prefetch, 6 blocks/CU), row-sum via MFMA ones-trick (no shuffle reduce),
// raw v_exp_f32, in-place masking. GEMMs unchanged from round 5.

#define DEV static __device__ __forceinline__

typedef __attribute__((ext_vector_type(8))) __bf16 bf16x8;           // MFMA A/B
typedef __attribute__((ext_vector_type(8))) unsigned short u16x8;    // staging
typedef __attribute__((ext_vector_type(4))) float f32x4;

DEV float bf2f(uint16_t u) { union { uint32_t u; float f; } v; v.u = ((uint32_t)u) << 16; return v.f; }
DEV uint16_t f2bf(float f) {
  union { float f; uint32_t u; } v; v.f = f;
  uint32_t r = v.u + 0x7fffu + ((v.u >> 16) & 1u);
  return (uint16_t)(r >> 16);
}
DEV uint16_t f2bf_hw(float f) { return __builtin_bit_cast(unsigned short, (__bf16)f); }

DEV bf16x8 asbf(u16x8 v) { return __builtin_bit_cast(bf16x8, v); }
DEV f32x4 mfma32(bf16x8 a, bf16x8 b, f32x4 c) {
  return __builtin_amdgcn_mfma_f32_16x16x32_bf16(a, b, c, 0, 0, 0);
}

// XOR swizzle: 16B slot s of row r lives at slot (s ^ (r&7)). Rows are 64 bf16 = 128B.
DEV int swz(int row, int slot) { return slot ^ (row & 7); }

DEV bf16x8 frag8(const uint16_t* l, int row, int slot) {
  u16x8 v = *(const u16x8*)((const char*)l + row * 128 + (swz(row, slot) << 4));
  return asbf(v);
}

// ---------------- dtype probe ----------------
__global__ void probe_k(const uint32_t* __restrict__ mask, uint32_t* __restrict__ flag) {
  flag[0] = (mask[1] & 0xFFFFu) ? 1u : 0u;   // 1 = bf16, 0 = f32
}

// ---------------- ingest convert ----------------
__global__ __launch_bounds__(256) void cvt_k(const void* __restrict__ src,
                                             uint16_t* __restrict__ dst, int n,
                                             const uint32_t* __restrict__ flag) {
  const int isbf = (int)flag[0];
  const int stride = gridDim.x * 256 * 8;
  for (int i = (blockIdx.x * 256 + threadIdx.x) * 8; i < n; i += stride) {
    if (isbf) {
      *(u16x8*)(dst + i) = *(const u16x8*)((const uint16_t*)src + i);
    } else {
      const float* sf = (const float*)src + i;
      u16x8 o;
      for (int j = 0; j < 8; j++) o[j] = f2bf(sf[j]);
      *(u16x8*)(dst + i) = o;
    }
  }
}

// ---------------- transpose+convert+scale: in[b][R][C] -> out[b][C][R] bf16 ----------------
__global__ __launch_bounds__(256) void transpose_k(const void* __restrict__ in_,
                                                   uint16_t* __restrict__ out, int R, int C,
                                                   float scale,
                                                   const uint32_t* __restrict__ flag) {
  __shared__ uint16_t t[32][33];
  const int isbf = (int)flag[0];
  const int b = blockIdx.z;
  const float* in_f = (const float*)in_ + (size_t)b * R * C;
  const uint16_t* in_u = (const uint16_t*)in_ + (size_t)b * R * C;
  out += (size_t)b * R * C;
  const int c0 = blockIdx.x * 32, r0 = blockIdx.y * 32;
  const int tx = threadIdx.x & 31, ty = threadIdx.x >> 5;
  for (int i = 0; i < 4; i++) {
    int r = ty + i * 8;
    size_t idx = (size_t)(r0 + r) * C + c0 + tx;
    uint16_t v;
    if (isbf) v = (scale == 1.0f) ? in_u[idx] : f2bf(bf2f(in_u[idx]) * scale);
    else      v = f2bf(in_f[idx] * scale);
    t[r][tx] = v;
  }
  __syncthreads();
  for (int i = 0; i < 4; i++) {
    int r = ty + i * 8;
    out[(size_t)(c0 + r) * R + r0 + tx] = t[tx][r];
  }
}

// ---------------- fused QKV projection (double-buffered) ----------------
__global__ __launch_bounds__(256) void proj_k(
    const uint16_t* __restrict__ A_qk, const uint16_t* __restrict__ A_v,
    const uint16_t* __restrict__ Wtq, const uint16_t* __restrict__ Wtk,
    const uint16_t* __restrict__ Wtv,
    uint16_t* __restrict__ Q, uint16_t* __restrict__ K, uint16_t* __restrict__ Vt) {
  __shared__ __attribute__((aligned(16))) uint16_t lA[2][128 * 64];
  __shared__ __attribute__((aligned(16))) uint16_t lB[2][64 * 64];
  const int tid = threadIdx.x, lane = tid & 63, wave = tid >> 6;
  const int g = lane >> 4;
  const int m0 = blockIdx.x * 128;
  const int h = blockIdx.y & 15, proj = blockIdx.y >> 4;
  const int b = blockIdx.z;
  const uint16_t* A = (proj == 2 ? A_v : A_qk) + (size_t)b * 2048 * 1024;
  const uint16_t* Bt = (proj == 0 ? Wtq : proj == 1 ? Wtk : Wtv) + (size_t)h * 64 * 1024;
  const int wm = wave >> 1, wn = wave & 1;
  f32x4 acc[4][2] = {};
  u16x8 ra[4], rb[2];
  const int rowA0 = tid >> 3, slotA = tid & 7;
  auto loadT = [&](int kt) {
    for (int i = 0; i < 4; i++)
      ra[i] = *(const u16x8*)(A + (size_t)(m0 + rowA0 + i * 32) * 1024 + kt + slotA * 8);
    for (int i = 0; i < 2; i++)
      rb[i] = *(const u16x8*)(Bt + (size_t)(rowA0 + i * 32) * 1024 + kt + slotA * 8);
  };
  auto writeT = [&](int buf) {
    for (int i = 0; i < 4; i++) {
      int row = rowA0 + i * 32;
      *(u16x8*)&lA[buf][(row * 8 + swz(row, slotA)) * 8] = ra[i];
    }
    for (int i = 0; i < 2; i++) {
      int row = rowA0 + i * 32;
      *(u16x8*)&lB[buf][(row * 8 + swz(row, slotA)) * 8] = rb[i];
    }
  };
  loadT(0);
  writeT(0);
  int cur = 0;
  for (int it = 0; it < 16; it++) {
    const int more = (it < 15);
    if (more) loadT((it + 1) * 64);
    __syncthreads();
    for (int kk = 0; kk < 2; kk++) {
      bf16x8 af[4], bfr[2];
      for (int fm = 0; fm < 4; fm++) af[fm] = frag8(lA[cur], wm * 64 + fm * 16 + (lane & 15), kk * 4 + g);
      for (int fn = 0; fn < 2; fn++) bfr[fn] = frag8(lB[cur], wn * 32 + fn * 16 + (lane & 15), kk * 4 + g);
      for (int fm = 0; fm < 4; fm++)
        for (int fn = 0; fn < 2; fn++)
          acc[fm][fn] = mfma32(af[fm], bfr[fn], acc[fm][fn]);
    }
    if (more) writeT(cur ^ 1);
    cur ^= 1;
  }
  const size_t bh = (size_t)(b * 16 + h);
  if (proj != 2) {
    uint16_t* outp = (proj == 0 ? Q : K);
    for (int fm = 0; fm < 4; fm++)
      for (int fn = 0; fn < 2; fn++)
        for (int r = 0; r < 4; r++) {
          int s = m0 + wm * 64 + fm * 16 + g * 4 + r;
          int e = wn * 32 + fn * 16 + (lane & 15);
          outp[(bh * 2048 + s) * 64 + e] = f2bf(acc[fm][fn][r]);
        }
  } else {
    __syncthreads();
    uint16_t* tv = lA[0];
    for (int fm = 0; fm < 4; fm++)
      for (int fn = 0; fn < 2; fn++)
        for (int r = 0; r < 4; r++) {
          int s = wm * 64 + fm * 16 + g * 4 + r;
          int e = wn * 32 + fn * 16 + (lane & 15);
          tv[e * 128 + s] = f2bf(acc[fm][fn][r]);
        }
    __syncthreads();
    for (int e = tid >> 4; e < 64; e += 16) {
      int s = (tid & 15) * 8;
      *(u16x8*)(Vt + (bh * 64 + e) * 2048 + m0 + s) = *(const u16x8*)&tv[e * 128 + s];
    }
  }
}

// ---------------- flash attention (log2 domain, MFMA row-sum, 24KB LDS) ----------------
// Q pre-scaled by 0.125*log2e. CAUSAL: grid.x=16, passes qt={x, 31-x}.
template <int CAUSAL>
__global__ __launch_bounds__(256) void attn_k(const uint16_t* __restrict__ Q,
                                              const uint16_t* __restrict__ K,
                                              const uint16_t* __restrict__ Vt,
                                              uint16_t* __restrict__ O) {
  __shared__ __attribute__((aligned(16))) uint16_t lK[64 * 64];
  __shared__ __attribute__((aligned(16))) uint16_t lV[64 * 64];
  __shared__ __attribute__((aligned(16))) uint16_t lP[4][16 * 64];
  const int tid = threadIdx.x, lane = tid & 63, wave = tid >> 6;
  const int g = lane >> 4;
  const int h = blockIdx.y, b = blockIdx.z;
  const size_t bh = (size_t)(b * 16 + h);
  const uint16_t* Qg = Q + bh * 2048 * 64;
  const uint16_t* Kg = K + bh * 2048 * 64;
  const uint16_t* Vg = Vt + bh * 64 * 2048;
  uint16_t* lPw = lP[wave];
  // all-ones B fragment for MFMA row-sum
  bf16x8 ones;
  for (int j = 0; j < 8; j++) ones[j] = (__bf16)1.0f;
  // P-store base addresses: addr(r,nf) = pbase[r] ^ (nf<<5)
  uint32_t pbase[4];
  for (int r = 0; r < 4; r++) {
    int row = g * 4 + r;
    pbase[r] = row * 128 + (((((lane & 15) >> 3)) ^ (row & 7)) << 4) + ((lane & 7) << 1);
  }
  u16x8 rk[2], rv[2];
  const int row0 = tid >> 3, slot0 = tid & 7;
  auto loadKV = [&](int kt) {
    for (int i = 0; i < 2; i++) {
      int row = row0 + i * 32;
      rk[i] = *(const u16x8*)(Kg + (size_t)(kt * 64 + row) * 64 + slot0 * 8);
      rv[i] = *(const u16x8*)(Vg + (size_t)row * 2048 + kt * 64 + slot0 * 8);
    }
  };
  auto writeKV = [&]() {
    for (int i = 0; i < 2; i++) {
      int row = row0 + i * 32;
      *(u16x8*)&lK[(row * 8 + swz(row, slot0)) * 8] = rk[i];
      *(u16x8*)&lV[(row * 8 + swz(row, slot0)) * 8] = rv[i];
    }
  };
  const int npass = CAUSAL ? 2 : 1;
  for (int pass = 0; pass < npass; pass++) {
    const int qt = CAUSAL ? (pass ? 31 - (int)blockIdx.x : (int)blockIdx.x) : (int)blockIdx.x;
    const int q0 = qt * 64;
    bf16x8 qf[2];
    {
      int row = q0 + wave * 16 + (lane & 15);
      for (int kk = 0; kk < 2; kk++)
        qf[kk] = asbf(*(const u16x8*)(Qg + (size_t)row * 64 + kk * 32 + g * 8));
    }
    f32x4 oacc[4] = {};
    f32x4 acc_l = {};
    float m_run[4];
    for (int r = 0; r < 4; r++) m_run[r] = -INFINITY;
    const int ktmax = CAUSAL ? qt : 31;
    loadKV(0);
    for (int kt = 0; kt <= ktmax; kt++) {
      const int more = (kt < ktmax);
      __syncthreads();          // previous tile's LDS reads complete
      writeKV();                // regs -> LDS (tile kt)
      __syncthreads();          // visible to all waves
      if (more) loadKV(kt + 1); // prefetch next in flight during compute
      // QK^T (log2 domain)
      f32x4 s[4] = {};
      for (int kk = 0; kk < 2; kk++)
        for (int nf = 0; nf < 4; nf++)
          s[nf] = mfma32(qf[kk], frag8(lK, nf * 16 + (lane & 15), kk * 4 + g), s[nf]);
      if (CAUSAL && kt == qt) {
        for (int nf = 0; nf < 4; nf++)
          for (int r = 0; r < 4; r++) {
            int qloc = wave * 16 + g * 4 + r;
            int kloc = nf * 16 + (lane & 15);
            if (kloc > qloc) s[nf][r] = -1e9f;
          }
      }
      // local row max; defer-max fast path
      float rloc[4];
      for (int r = 0; r < 4; r++)
        rloc[r] = fmaxf(fmaxf(s[0][r], s[1][r]), fmaxf(s[2][r], s[3][r]));
      bool ok = true;
      for (int r = 0; r < 4; r++) ok = ok && (rloc[r] <= m_run[r] + 8.0f);
      if (!__all(ok)) {
        float rmax[4];
        for (int r = 0; r < 4; r++) rmax[r] = rloc[r];
        for (int m = 1; m < 16; m <<= 1)
          for (int r = 0; r < 4; r++) rmax[r] = fmaxf(rmax[r], __shfl_xor(rmax[r], m));
        for (int r = 0; r < 4; r++) {
          float mn = fmaxf(m_run[r], rmax[r]);
          float alpha = __builtin_amdgcn_exp2f(m_run[r] - mn);
          m_run[r] = mn;
          acc_l[r] *= alpha;
          for (int df = 0; df < 4; df++) oacc[df][r] *= alpha;
        }
      }
      for (int nf = 0; nf < 4; nf++)
        for (int r = 0; r < 4; r++) {
          float p = __builtin_amdgcn_exp2f(s[nf][r] - m_run[r]);
          *(uint16_t*)((char*)lPw + (pbase[r] ^ (nf << 5))) = f2bf_hw(p);
        }
      // PV + MFMA row-sum (l = P @ ones)
      for (int kk = 0; kk < 2; kk++) {
        bf16x8 pa = frag8(lPw, lane & 15, kk * 4 + g);
        acc_l = mfma32(pa, ones, acc_l);
        for (int df = 0; df < 4; df++)
          oacc[df] = mfma32(pa, frag8(lV, df * 16 + (lane & 15), kk * 4 + g), oacc[df]);
      }
    }
    float inv[4];
    for (int r = 0; r < 4; r++) inv[r] = 1.0f / acc_l[r];
    for (int df = 0; df < 4; df++)
      for (int r = 0; r < 4; r++) {
        int srow = q0 + wave * 16 + g * 4 + r;
        int e = df * 16 + (lane & 15);
        O[((size_t)b * 2048 + srow) * 1024 + h * 64 + e] = f2bf(oacc[df][r] * inv[r]);
      }
  }
}

// ---------------- FFN GEMM: C[M,N] = A[M,K] @ Bt[N,K]^T (+bias, relu), dbuf ----------------
template <int RELU>
__global__ __launch_bounds__(256) void ff_k(const uint16_t* __restrict__ A,
                                            const uint16_t* __restrict__ Bt,
                                            const uint16_t* __restrict__ bias,
                                            uint16_t* __restrict__ C, int Kdim, int N) {
  __shared__ __attribute__((aligned(16))) uint16_t lA[2][128 * 64];
  __shared__ __attribute__((aligned(16))) uint16_t lB[2][128 * 64];
  const int tid = threadIdx.x, lane = tid & 63, wave = tid >> 6;
  const int g = lane >> 4;
  const int m0 = blockIdx.x * 128, n0 = blockIdx.y * 128;
  const int wm = wave >> 1, wn = wave & 1;
  f32x4 acc[4][4] = {};
  u16x8 ra[4], rb[4];
  const int row0 = tid >> 3, slot0 = tid & 7;
  auto loadT = [&](int kt) {
    for (int i = 0; i < 4; i++) {
      int row = row0 + i * 32;
      ra[i] = *(const u16x8*)(A + (size_t)(m0 + row) * Kdim + kt + slot0 * 8);
      rb[i] = *(const u16x8*)(Bt + (size_t)(n0 + row) * Kdim + kt + slot0 * 8);
    }
  };
  auto writeT = [&](int buf) {
    for (int i = 0; i < 4; i++) {
      int row = row0 + i * 32;
      *(u16x8*)&lA[buf][(row * 8 + swz(row, slot0)) * 8] = ra[i];
      *(u16x8*)&lB[buf][(row * 8 + swz(row, slot0)) * 8] = rb[i];
    }
  };
  loadT(0);
  writeT(0);
  int cur = 0;
  const int nit = Kdim >> 6;
  for (int it = 0; it < nit; it++) {
    const int more = (it < nit - 1);
    if (more) loadT((it + 1) * 64);
    __syncthreads();
    for (int kk = 0; kk < 2; kk++) {
      bf16x8 af[4], bfr[4];
      for (int fm = 0; fm < 4; fm++) af[fm] = frag8(lA[cur], wm * 64 + fm * 16 + (lane & 15), kk * 4 + g);
      for (int fn = 0; fn < 4; fn++) bfr[fn] = frag8(lB[cur], wn * 64 + fn * 16 + (lane & 15), kk * 4 + g);
      for (int fm = 0; fm < 4; fm++)
        for (int fn = 0; fn < 4; fn++)
          acc[fm][fn] = mfma32(af[fm], bfr[fn], acc[fm][fn]);
    }
    if (more) writeT(cur ^ 1);
    cur ^= 1;
  }
  for (int fm = 0; fm < 4; fm++)
    for (int fn = 0; fn < 4; fn++) {
      int col = n0 + wn * 64 + fn * 16 + (lane & 15);
      float bv = bf2f(bias[col]);
      for (int r = 0; r < 4; r++) {
        int row = m0 + wm * 64 + fm * 16 + g * 4 + r;
        float v = acc[fm][fn][r] + bv;
        if (RELU) v = fmaxf(v, 0.f);
        C[(size_t)row * N + col] = f2bf(v);
      }
    }
}

// ---------------- output store ----------------
__global__ __launch_bounds__(256) void store_k(const uint16_t* __restrict__ yb,
                                               void* __restrict__ out, int n,
                                               const uint32_t* __restrict__ flag) {
  const int isbf = (int)flag[0];
  const int stride = gridDim.x * 256 * 8;
  for (int i = (blockIdx.x * 256 + threadIdx.x) * 8; i < n; i += stride) {
    u16x8 v = *(const u16x8*)(yb + i);
    if (isbf) {
      *(u16x8*)((uint16_t*)out + i) = v;
    } else {
      float* of = (float*)out + i;
      for (int j = 0; j < 8; j++) of[j] = bf2f(v[j]);
    }
  }
}

extern "C" void kernel_launch(void* const* d_in, const int* in_sizes, int n_in,
                              void* d_out, int out_size, void* d_ws, size_t ws_size,
                              hipStream_t stream) {
  const void* de_x = d_in[0];
  const void* en_x = d_in[1];
  const void* mask = d_in[2];
  const void* Wq = d_in[3];
  const void* Wk = d_in[4];
  const void* Wv = d_in[5];
  const void* W1 = d_in[6];
  const void* b1 = d_in[7];
  const void* W2 = d_in[8];
  const void* b2 = d_in[9];

  uint16_t* ws = (uint16_t*)d_ws;
  const size_t M1 = (size_t)1 << 20;
  uint32_t* flag = (uint32_t*)ws;
  uint16_t* b1c = ws + 1024;
  uint16_t* b2c = ws + 4096;
  uint16_t* Wtq = ws + 1 * M1;                 // [16][64][1024], scaled 0.125*log2e
  uint16_t* Wtk = ws + 2 * M1;
  uint16_t* Wtv = ws + 3 * M1;
  uint16_t* W1t = ws + 4 * M1;                 // [2048][1024]
  uint16_t* W2t = ws + 6 * M1;                 // [1024][2048]
  uint16_t* de_c = ws + 8 * M1;                // [4096][1024]
  uint16_t* en_c = ws + 12 * M1;
  uint16_t* Qb  = ws + 16 * M1;                // [B,H,S,64]
  uint16_t* Kb  = ws + 20 * M1;
  uint16_t* Vtb = ws + 24 * M1;                // [B,H,64,S]
  uint16_t* h1  = ws + 28 * M1;
  uint16_t* h2  = ws + 32 * M1;
  uint16_t* ff1 = Qb;                          // reuse
  uint16_t* yb  = Vtb;                         // reuse

  const int NX = 2 * 2048 * 1024;
  dim3 blk(256);

  probe_k<<<1, 1, 0, stream>>>((const uint32_t*)mask, flag);
  cvt_k<<<2048, blk, 0, stream>>>(de_x, de_c, NX, flag);
  cvt_k<<<2048, blk, 0, stream>>>(en_x, en_c, NX, flag);
  cvt_k<<<1, blk, 0, stream>>>(b1, b1c, 2048, flag);
  cvt_k<<<1, blk, 0, stream>>>(b2, b2c, 1024, flag);
  transpose_k<<<dim3(2, 32, 16), blk, 0, stream>>>(Wq, Wtq, 1024, 64, 0.180336880f, flag); // 0.125*log2(e)
  transpose_k<<<dim3(2, 32, 16), blk, 0, stream>>>(Wk, Wtk, 1024, 64, 1.0f, flag);
  transpose_k<<<dim3(2, 32, 16), blk, 0, stream>>>(Wv, Wtv, 1024, 64, 1.0f, flag);
  transpose_k<<<dim3(64, 32, 1), blk, 0, stream>>>(W1, W1t, 1024, 2048, 1.0f, flag);
  transpose_k<<<dim3(32, 64, 1), blk, 0, stream>>>(W2, W2t, 2048, 1024, 1.0f, flag);
  // MHA1: q=k=v=de_x, causal (paired q-tiles)
  proj_k<<<dim3(16, 48, 2), blk, 0, stream>>>(de_c, de_c, Wtq, Wtk, Wtv, Qb, Kb, Vtb);
  attn_k<1><<<dim3(16, 16, 2), blk, 0, stream>>>(Qb, Kb, Vtb, h1);
  // MHA2: q=k=en_x, v=h1, no mask
  proj_k<<<dim3(16, 48, 2), blk, 0, stream>>>(en_c, h1, Wtq, Wtk, Wtv, Qb, Kb, Vtb);
  attn_k<0><<<dim3(32, 16, 2), blk, 0, stream>>>(Qb, Kb, Vtb, h2);
  // FFN
  ff_k<1><<<dim3(32, 16), blk, 0, stream>>>(h2, W1t, b1c, ff1, 1024, 2048);
  ff_k<0><<<dim3(32, 8), blk, 0, stream>>>(ff1, W2t, b2c, yb, 2048, 1024);
  store_k<<<2048, blk, 0, stream>>>(yb, d_out, out_size, flag);
}